// Round 1
// baseline (14424.634 us; speedup 1.0000x reference)
//
#include <hip/hip_runtime.h>

#define EPS 1e-5f

// ---------------------------------------------------------------------------
// scatter_gemm_rpl: row-per-lane. Grid is k-major: each block serves a single
// k, stages W[k] (CIN*COUT floats) into LDS once, then each lane owns one row:
// gathers x[in_idx[r]] as float4s, computes all COUT outputs with LDS-broadcast
// W reads, and atomicAdds the contiguous COUT-float result into out[out_idx[r]].
// ---------------------------------------------------------------------------
template <int CIN, int COUT>
__global__ __launch_bounds__(256) void scatter_gemm_rpl(
    const float* __restrict__ x, const float* __restrict__ W,
    const int* __restrict__ in_idx, const int* __restrict__ out_idx,
    float* __restrict__ out, int P, int blocks_per_k)
{
    __shared__ float Wlds[CIN * COUT];
    const int k = blockIdx.x / blocks_per_k;
    const int rowblk = blockIdx.x % blocks_per_k;

    // Stage W[k] into LDS (coalesced float4 loads, all threads).
    const float* Wk = W + (size_t)k * (CIN * COUT);
    for (int t = threadIdx.x * 4; t < CIN * COUT; t += 256 * 4) {
        *(float4*)&Wlds[t] = *(const float4*)&Wk[t];
    }
    __syncthreads();

    const int p = rowblk * 256 + (int)threadIdx.x;
    if (p >= P) return;
    const int r = k * P + p;

    const int in   = in_idx[r];
    const int orow = out_idx[r];
    const float4* __restrict__ xr4 = (const float4*)(x + (size_t)in * CIN);

    float acc[COUT];
#pragma unroll
    for (int o = 0; o < COUT; ++o) acc[o] = 0.f;

#pragma unroll 2
    for (int i4 = 0; i4 < CIN / 4; ++i4) {
        const float4 xv = xr4[i4];
#pragma unroll
        for (int j = 0; j < 4; ++j) {
            const float xsj = (j == 0) ? xv.x : (j == 1) ? xv.y : (j == 2) ? xv.z : xv.w;
            const float* __restrict__ wrow = &Wlds[(i4 * 4 + j) * COUT];
#pragma unroll
            for (int o4 = 0; o4 < COUT / 4; ++o4) {
                const float4 w = *(const float4*)&wrow[o4 * 4];
                acc[o4 * 4 + 0] = fmaf(xsj, w.x, acc[o4 * 4 + 0]);
                acc[o4 * 4 + 1] = fmaf(xsj, w.y, acc[o4 * 4 + 1]);
                acc[o4 * 4 + 2] = fmaf(xsj, w.z, acc[o4 * 4 + 2]);
                acc[o4 * 4 + 3] = fmaf(xsj, w.w, acc[o4 * 4 + 3]);
            }
        }
    }

    float* __restrict__ orp = out + (size_t)orow * COUT;
#pragma unroll
    for (int o = 0; o < COUT; ++o) atomicAdd(&orp[o], acc[o]);
}

// ---------------------------------------------------------------------------
// reduce_stats: per-channel sum and sum-of-squares over n_rows rows.
// stats[0..COUT) = sum, stats[COUT..2*COUT) = sumsq. Must be pre-zeroed.
// ---------------------------------------------------------------------------
template <int COUT>
__global__ __launch_bounds__(256) void reduce_stats(
    const float* __restrict__ out, float* __restrict__ stats, int n_rows)
{
    const int RPP = 256 / COUT;  // rows per pass per block
    int c = threadIdx.x % COUT;
    int g = threadIdx.x / COUT;
    float s = 0.f, ss = 0.f;
    for (long long row = (long long)blockIdx.x * RPP + g; row < n_rows;
         row += (long long)gridDim.x * RPP) {
        float v = out[row * COUT + c];
        s += v;
        ss += v * v;
    }
    __shared__ float sh_s[256];
    __shared__ float sh_ss[256];
    sh_s[threadIdx.x] = s;
    sh_ss[threadIdx.x] = ss;
    __syncthreads();
    for (int off = 128; off >= COUT; off >>= 1) {
        if (threadIdx.x < off) {
            sh_s[threadIdx.x] += sh_s[threadIdx.x + off];
            sh_ss[threadIdx.x] += sh_ss[threadIdx.x + off];
        }
        __syncthreads();
    }
    if (threadIdx.x < COUT) {
        atomicAdd(&stats[c], sh_s[c]);
        atomicAdd(&stats[COUT + c], sh_ss[c]);
    }
}

// ---------------------------------------------------------------------------
// bn_skip: y = (v - mean) * rsqrt(var + eps) * gamma + beta + skip, in place.
// Processes float4 (4 consecutive channels) per thread.
// ---------------------------------------------------------------------------
template <int COUT>
__global__ __launch_bounds__(256) void bn_skip(
    float* __restrict__ out, const float* __restrict__ skip,
    const float* __restrict__ gamma, const float* __restrict__ beta,
    const float* __restrict__ stats, int n_rows)
{
    const int C4 = COUT / 4;
    long long idx = (long long)blockIdx.x * blockDim.x + threadIdx.x;
    long long total = (long long)n_rows * C4;
    if (idx >= total) return;
    int c4 = (int)(idx % C4);
    float4 v = ((const float4*)out)[idx];
    float4 sk = ((const float4*)skip)[idx];
    float inv_n = 1.f / (float)n_rows;
    float r[4] = {v.x, v.y, v.z, v.w};
    float skv[4] = {sk.x, sk.y, sk.z, sk.w};
#pragma unroll
    for (int j = 0; j < 4; ++j) {
        int c = c4 * 4 + j;
        float mean = stats[c] * inv_n;
        float var = stats[COUT + c] * inv_n - mean * mean;
        float scale = rsqrtf(var + EPS) * gamma[c];
        r[j] = (r[j] - mean) * scale + beta[c] + skv[j];
    }
    float4 res = {r[0], r[1], r[2], r[3]};
    ((float4*)out)[idx] = res;
}

extern "C" void kernel_launch(void* const* d_in, const int* in_sizes, int n_in,
                              void* d_out, int out_size, void* d_ws, size_t ws_size,
                              hipStream_t stream) {
    const float* x3    = (const float*)d_in[0];
    const float* skip3 = (const float*)d_in[1];
    const float* skip2 = (const float*)d_in[2];
    const float* skip1 = (const float*)d_in[3];
    const float* W3    = (const float*)d_in[4];
    const float* W2    = (const float*)d_in[5];
    const float* W1    = (const float*)d_in[6];
    const float* gamma3 = (const float*)d_in[7];
    const float* beta3  = (const float*)d_in[8];
    const float* gamma2 = (const float*)d_in[9];
    const float* beta2  = (const float*)d_in[10];
    const float* gamma1 = (const float*)d_in[11];
    const float* beta1  = (const float*)d_in[12];
    const int* in_idx3  = (const int*)d_in[13];
    const int* out_idx3 = (const int*)d_in[14];
    const int* in_idx2  = (const int*)d_in[15];
    const int* out_idx2 = (const int*)d_in[16];
    const int* in_idx1  = (const int*)d_in[17];
    const int* out_idx1 = (const int*)d_in[18];

    const int N3 = 40000, N2 = 160000, N1 = 640000, N0 = 2560000;
    const int K = 9;

    float* buf3  = (float*)d_ws;                    // N2 * 64
    float* buf2  = buf3 + (size_t)N2 * 64;          // N1 * 32
    float* stats = buf2 + (size_t)N1 * 32;          // 128 floats

    float* outp = (float*)d_out;                    // N0 * 32

    // ---------------- Level 3: x3[N3,128] -> buf3[N2,64] ----------------
    hipMemsetAsync(buf3, 0, (size_t)N2 * 64 * sizeof(float), stream);
    hipMemsetAsync(stats, 0, 128 * sizeof(float), stream);
    {
        int bpk = (N3 + 255) / 256;  // 157 (last block partially active)
        scatter_gemm_rpl<128, 64><<<K * bpk, 256, 0, stream>>>(
            x3, W3, in_idx3, out_idx3, buf3, N3, bpk);
    }
    reduce_stats<64><<<1024, 256, 0, stream>>>(buf3, stats, N2);
    {
        long long tot = (long long)N2 * (64 / 4);
        bn_skip<64><<<(int)((tot + 255) / 256), 256, 0, stream>>>(
            buf3, skip3, gamma3, beta3, stats, N2);
    }

    // ---------------- Level 2: buf3[N2,64] -> buf2[N1,32] ----------------
    hipMemsetAsync(buf2, 0, (size_t)N1 * 32 * sizeof(float), stream);
    hipMemsetAsync(stats, 0, 128 * sizeof(float), stream);
    {
        int bpk = N2 / 256;  // 625 exact
        scatter_gemm_rpl<64, 32><<<K * bpk, 256, 0, stream>>>(
            buf3, W2, in_idx2, out_idx2, buf2, N2, bpk);
    }
    reduce_stats<32><<<2048, 256, 0, stream>>>(buf2, stats, N1);
    {
        long long tot = (long long)N1 * (32 / 4);
        bn_skip<32><<<(int)((tot + 255) / 256), 256, 0, stream>>>(
            buf2, skip2, gamma2, beta2, stats, N1);
    }

    // ---------------- Level 1: buf2[N1,32] -> d_out[N0,32] ----------------
    hipMemsetAsync(outp, 0, (size_t)N0 * 32 * sizeof(float), stream);
    hipMemsetAsync(stats, 0, 128 * sizeof(float), stream);
    {
        int bpk = N1 / 256;  // 2500 exact
        scatter_gemm_rpl<32, 32><<<K * bpk, 256, 0, stream>>>(
            buf2, W1, in_idx1, out_idx1, outp, N1, bpk);
    }
    reduce_stats<32><<<4096, 256, 0, stream>>>(outp, stats, N0);
    {
        long long tot = (long long)N0 * (32 / 4);
        bn_skip<32><<<(int)((tot + 255) / 256), 256, 0, stream>>>(
            outp, skip1, gamma1, beta1, stats, N0);
    }
}

// Round 2
// 2991.177 us; speedup vs baseline: 4.8224x; 4.8224x over previous
//
#include <hip/hip_runtime.h>

#define EPS 1e-5f

// ---------------------------------------------------------------------------
// scatter_gemm_wreg: COUT lanes per row (lane = output channel o), so the
// per-row atomicAdd is one instruction covering a contiguous COUT*4B segment
// (coalesced L2 atomic, write traffic == payload). k lives in gridDim.y, so
// each thread loads its W column W[k][:,o] into registers ONCE and reuses it
// across all rows its group processes. x rows are read as broadcast float4s.
// Per row-pair wave: ~CIN/4+2 VMEM instrs + CIN FMA instrs + 1 atomic instr.
// ---------------------------------------------------------------------------
template <int CIN, int COUT, int RPB>
__global__ __launch_bounds__(256) void scatter_gemm_wreg(
    const float* __restrict__ x, const float* __restrict__ W,
    const int* __restrict__ in_idx, const int* __restrict__ out_idx,
    float* __restrict__ out, int P)
{
    const int GROUPS = 256 / COUT;  // row-groups per block
    const int k = blockIdx.y;
    const int o = threadIdx.x % COUT;
    const int g = threadIdx.x / COUT;

    // Load W[k][:, o] into registers (coalesced across lanes; once per block).
    float wcol[CIN];
    const float* __restrict__ Wk = W + (size_t)k * CIN * COUT + o;
#pragma unroll
    for (int i = 0; i < CIN; ++i) wcol[i] = Wk[(size_t)i * COUT];

    const int p0 = blockIdx.x * RPB;
    const int p1 = (p0 + RPB < P) ? (p0 + RPB) : P;
    const int rbase = k * P;

    for (int p = p0 + g; p < p1; p += GROUPS) {
        const int r = rbase + p;
        const int in   = in_idx[r];
        const int orow = out_idx[r];
        const float4* __restrict__ xr4 = (const float4*)(x + (size_t)in * CIN);
        float acc = 0.f;
#pragma unroll
        for (int i4 = 0; i4 < CIN / 4; ++i4) {
            const float4 xv = xr4[i4];
            acc = fmaf(xv.x, wcol[4 * i4 + 0], acc);
            acc = fmaf(xv.y, wcol[4 * i4 + 1], acc);
            acc = fmaf(xv.z, wcol[4 * i4 + 2], acc);
            acc = fmaf(xv.w, wcol[4 * i4 + 3], acc);
        }
        atomicAdd(&out[(size_t)orow * COUT + o], acc);
    }
}

// ---------------------------------------------------------------------------
// reduce_stats: per-channel sum and sum-of-squares over n_rows rows.
// stats[0..COUT) = sum, stats[COUT..2*COUT) = sumsq. Must be pre-zeroed.
// ---------------------------------------------------------------------------
template <int COUT>
__global__ __launch_bounds__(256) void reduce_stats(
    const float* __restrict__ out, float* __restrict__ stats, int n_rows)
{
    const int RPP = 256 / COUT;  // rows per pass per block
    int c = threadIdx.x % COUT;
    int g = threadIdx.x / COUT;
    float s = 0.f, ss = 0.f;
    for (long long row = (long long)blockIdx.x * RPP + g; row < n_rows;
         row += (long long)gridDim.x * RPP) {
        float v = out[row * COUT + c];
        s += v;
        ss += v * v;
    }
    __shared__ float sh_s[256];
    __shared__ float sh_ss[256];
    sh_s[threadIdx.x] = s;
    sh_ss[threadIdx.x] = ss;
    __syncthreads();
    for (int off = 128; off >= COUT; off >>= 1) {
        if (threadIdx.x < off) {
            sh_s[threadIdx.x] += sh_s[threadIdx.x + off];
            sh_ss[threadIdx.x] += sh_ss[threadIdx.x + off];
        }
        __syncthreads();
    }
    if (threadIdx.x < COUT) {
        atomicAdd(&stats[c], sh_s[c]);
        atomicAdd(&stats[COUT + c], sh_ss[c]);
    }
}

// ---------------------------------------------------------------------------
// bn_skip: y = (v - mean) * rsqrt(var + eps) * gamma + beta + skip, in place.
// Processes float4 (4 consecutive channels) per thread.
// ---------------------------------------------------------------------------
template <int COUT>
__global__ __launch_bounds__(256) void bn_skip(
    float* __restrict__ out, const float* __restrict__ skip,
    const float* __restrict__ gamma, const float* __restrict__ beta,
    const float* __restrict__ stats, int n_rows)
{
    const int C4 = COUT / 4;
    long long idx = (long long)blockIdx.x * blockDim.x + threadIdx.x;
    long long total = (long long)n_rows * C4;
    if (idx >= total) return;
    int c4 = (int)(idx % C4);
    float4 v = ((const float4*)out)[idx];
    float4 sk = ((const float4*)skip)[idx];
    float inv_n = 1.f / (float)n_rows;
    float r[4] = {v.x, v.y, v.z, v.w};
    float skv[4] = {sk.x, sk.y, sk.z, sk.w};
#pragma unroll
    for (int j = 0; j < 4; ++j) {
        int c = c4 * 4 + j;
        float mean = stats[c] * inv_n;
        float var = stats[COUT + c] * inv_n - mean * mean;
        float scale = rsqrtf(var + EPS) * gamma[c];
        r[j] = (r[j] - mean) * scale + beta[c] + skv[j];
    }
    float4 res = {r[0], r[1], r[2], r[3]};
    ((float4*)out)[idx] = res;
}

extern "C" void kernel_launch(void* const* d_in, const int* in_sizes, int n_in,
                              void* d_out, int out_size, void* d_ws, size_t ws_size,
                              hipStream_t stream) {
    const float* x3    = (const float*)d_in[0];
    const float* skip3 = (const float*)d_in[1];
    const float* skip2 = (const float*)d_in[2];
    const float* skip1 = (const float*)d_in[3];
    const float* W3    = (const float*)d_in[4];
    const float* W2    = (const float*)d_in[5];
    const float* W1    = (const float*)d_in[6];
    const float* gamma3 = (const float*)d_in[7];
    const float* beta3  = (const float*)d_in[8];
    const float* gamma2 = (const float*)d_in[9];
    const float* beta2  = (const float*)d_in[10];
    const float* gamma1 = (const float*)d_in[11];
    const float* beta1  = (const float*)d_in[12];
    const int* in_idx3  = (const int*)d_in[13];
    const int* out_idx3 = (const int*)d_in[14];
    const int* in_idx2  = (const int*)d_in[15];
    const int* out_idx2 = (const int*)d_in[16];
    const int* in_idx1  = (const int*)d_in[17];
    const int* out_idx1 = (const int*)d_in[18];

    const int N3 = 40000, N2 = 160000, N1 = 640000, N0 = 2560000;
    const int K = 9;

    float* buf3  = (float*)d_ws;                    // N2 * 64
    float* buf2  = buf3 + (size_t)N2 * 64;          // N1 * 32
    float* stats = buf2 + (size_t)N1 * 32;          // 128 floats

    float* outp = (float*)d_out;                    // N0 * 32

    // ---------------- Level 3: x3[N3,128] -> buf3[N2,64] ----------------
    hipMemsetAsync(buf3, 0, (size_t)N2 * 64 * sizeof(float), stream);
    hipMemsetAsync(stats, 0, 128 * sizeof(float), stream);
    {
        const int RPB = 64;
        dim3 grid((N3 + RPB - 1) / RPB, K);
        scatter_gemm_wreg<128, 64, RPB><<<grid, 256, 0, stream>>>(
            x3, W3, in_idx3, out_idx3, buf3, N3);
    }
    reduce_stats<64><<<1024, 256, 0, stream>>>(buf3, stats, N2);
    {
        long long tot = (long long)N2 * (64 / 4);
        bn_skip<64><<<(int)((tot + 255) / 256), 256, 0, stream>>>(
            buf3, skip3, gamma3, beta3, stats, N2);
    }

    // ---------------- Level 2: buf3[N2,64] -> buf2[N1,32] ----------------
    hipMemsetAsync(buf2, 0, (size_t)N1 * 32 * sizeof(float), stream);
    hipMemsetAsync(stats, 0, 128 * sizeof(float), stream);
    {
        const int RPB = 64;
        dim3 grid((N2 + RPB - 1) / RPB, K);
        scatter_gemm_wreg<64, 32, RPB><<<grid, 256, 0, stream>>>(
            buf3, W2, in_idx2, out_idx2, buf2, N2);
    }
    reduce_stats<32><<<2048, 256, 0, stream>>>(buf2, stats, N1);
    {
        long long tot = (long long)N1 * (32 / 4);
        bn_skip<32><<<(int)((tot + 255) / 256), 256, 0, stream>>>(
            buf2, skip2, gamma2, beta2, stats, N1);
    }

    // ---------------- Level 1: buf2[N1,32] -> d_out[N0,32] ----------------
    hipMemsetAsync(outp, 0, (size_t)N0 * 32 * sizeof(float), stream);
    hipMemsetAsync(stats, 0, 128 * sizeof(float), stream);
    {
        const int RPB = 64;
        dim3 grid((N1 + RPB - 1) / RPB, K);
        scatter_gemm_wreg<32, 32, RPB><<<grid, 256, 0, stream>>>(
            buf2, W1, in_idx1, out_idx1, outp, N1);
    }
    reduce_stats<32><<<4096, 256, 0, stream>>>(outp, stats, N0);
    {
        long long tot = (long long)N0 * (32 / 4);
        bn_skip<32><<<(int)((tot + 255) / 256), 256, 0, stream>>>(
            outp, skip1, gamma1, beta1, stats, N0);
    }
}

// Round 4
// 2947.310 us; speedup vs baseline: 4.8942x; 1.0149x over previous
//
#include <hip/hip_runtime.h>

#define EPS 1e-5f

// ---------------------------------------------------------------------------
// scatter_gemm_wreg: COUT lanes per row (lane = output channel o). One
// coalesced atomic per row. k in gridDim.y so W[k][:,o] lives in registers.
// Used for level 1 (CIN=32, COUT=32) where wcol fits in 32 VGPRs.
// ---------------------------------------------------------------------------
template <int CIN, int COUT, int RPB>
__global__ __launch_bounds__(256) void scatter_gemm_wreg(
    const float* __restrict__ x, const float* __restrict__ W,
    const int* __restrict__ in_idx, const int* __restrict__ out_idx,
    float* __restrict__ out, int P)
{
    const int GROUPS = 256 / COUT;  // row-groups per block
    const int k = blockIdx.y;
    const int o = threadIdx.x % COUT;
    const int g = threadIdx.x / COUT;

    float wcol[CIN];
    const float* __restrict__ Wk = W + (size_t)k * CIN * COUT + o;
#pragma unroll
    for (int i = 0; i < CIN; ++i) wcol[i] = Wk[(size_t)i * COUT];

    const int p0 = blockIdx.x * RPB;
    const int p1 = (p0 + RPB < P) ? (p0 + RPB) : P;
    const int rbase = k * P;

    for (int p = p0 + g; p < p1; p += GROUPS) {
        const int r = rbase + p;
        const int in   = in_idx[r];
        const int orow = out_idx[r];
        const float4* __restrict__ xr4 = (const float4*)(x + (size_t)in * CIN);
        float acc = 0.f;
#pragma unroll
        for (int i4 = 0; i4 < CIN / 4; ++i4) {
            const float4 xv = xr4[i4];
            acc = fmaf(xv.x, wcol[4 * i4 + 0], acc);
            acc = fmaf(xv.y, wcol[4 * i4 + 1], acc);
            acc = fmaf(xv.z, wcol[4 * i4 + 2], acc);
            acc = fmaf(xv.w, wcol[4 * i4 + 3], acc);
        }
        atomicAdd(&out[(size_t)orow * COUT + o], acc);
    }
}

// ---------------------------------------------------------------------------
// scatter_gemm_h2: CIN split across lane-halves to halve wcol register
// pressure. 64 lanes per row: o = lane&31 (COUT must be 32), h = lane>>5
// selects which CIN-half this lane accumulates. Partial dots combined with
// __shfl_xor(32); h==0 half issues the coalesced 128-B atomic.
// Used for level 2 (CIN=64 -> wcol[32], VGPR ~50 instead of ~100).
// ---------------------------------------------------------------------------
template <int CIN, int RPB>
__global__ __launch_bounds__(256) void scatter_gemm_h2(
    const float* __restrict__ x, const float* __restrict__ W,
    const int* __restrict__ in_idx, const int* __restrict__ out_idx,
    float* __restrict__ out, int P)
{
    const int COUT = 32;
    const int HC = CIN / 2;
    const int WAVES = 256 / 64;            // 4 rows in flight per block
    const int k = blockIdx.y;
    const int lane = threadIdx.x & 63;
    const int w = threadIdx.x >> 6;
    const int o = lane & 31;
    const int h = lane >> 5;

    float wcol[HC];
    const float* __restrict__ Wk =
        W + (size_t)k * CIN * COUT + (size_t)h * HC * COUT + o;
#pragma unroll
    for (int i = 0; i < HC; ++i) wcol[i] = Wk[(size_t)i * COUT];

    const int p0 = blockIdx.x * RPB;
    const int p1 = (p0 + RPB < P) ? (p0 + RPB) : P;
    const int rbase = k * P;

    for (int p = p0 + w; p < p1; p += WAVES) {
        const int r = rbase + p;
        const int in   = in_idx[r];
        const int orow = out_idx[r];
        const float4* __restrict__ xr4 =
            (const float4*)(x + (size_t)in * CIN + h * HC);
        float acc = 0.f;
#pragma unroll
        for (int i4 = 0; i4 < HC / 4; ++i4) {
            const float4 xv = xr4[i4];
            acc = fmaf(xv.x, wcol[4 * i4 + 0], acc);
            acc = fmaf(xv.y, wcol[4 * i4 + 1], acc);
            acc = fmaf(xv.z, wcol[4 * i4 + 2], acc);
            acc = fmaf(xv.w, wcol[4 * i4 + 3], acc);
        }
        acc += __shfl_xor(acc, 32);
        if (h == 0) atomicAdd(&out[(size_t)orow * COUT + o], acc);
    }
}

// ---------------------------------------------------------------------------
// scatter_gemm_l3_h2: level 3 (CIN=128, COUT=64). 128 threads per row:
// o = lane2&63, h = lane2>>6 selects CIN-half -> wcol[64] (VGPR ~80 instead
// of ~160+). Partials combined through a tiny LDS buffer; h==0 wave issues
// the coalesced 256-B atomic. Grids are exact (no tail), loop is uniform so
// the __syncthreads inside is safe.
// ---------------------------------------------------------------------------
template <int RPB>
__global__ __launch_bounds__(256) void scatter_gemm_l3_h2(
    const float* __restrict__ x, const float* __restrict__ W,
    const int* __restrict__ in_idx, const int* __restrict__ out_idx,
    float* __restrict__ out, int P)
{
    const int CIN = 128, COUT = 64;
    const int lane2 = threadIdx.x & 127;
    const int rg = threadIdx.x >> 7;       // 2 rows in flight per block
    const int o = lane2 & 63;
    const int h = lane2 >> 6;
    const int k = blockIdx.y;

    float wcol[64];
    const float* __restrict__ Wk =
        W + (size_t)k * CIN * COUT + (size_t)h * 64 * COUT + o;
#pragma unroll
    for (int i = 0; i < 64; ++i) wcol[i] = Wk[(size_t)i * COUT];

    __shared__ float part[2][64];

    const int p0 = blockIdx.x * RPB;
    const int rbase = k * P;

    for (int it = 0; it < RPB / 2; ++it) {
        const int p = p0 + it * 2 + rg;    // exact grid: p < P always
        const int r = rbase + p;
        const int in   = in_idx[r];
        const int orow = out_idx[r];
        const float4* __restrict__ xr4 =
            (const float4*)(x + (size_t)in * CIN + h * 64);
        float acc = 0.f;
#pragma unroll
        for (int i4 = 0; i4 < 16; ++i4) {
            const float4 xv = xr4[i4];
            acc = fmaf(xv.x, wcol[4 * i4 + 0], acc);
            acc = fmaf(xv.y, wcol[4 * i4 + 1], acc);
            acc = fmaf(xv.z, wcol[4 * i4 + 2], acc);
            acc = fmaf(xv.w, wcol[4 * i4 + 3], acc);
        }
        if (h == 1) part[rg][o] = acc;
        __syncthreads();
        if (h == 0) {
            acc += part[rg][o];
            atomicAdd(&out[(size_t)orow * COUT + o], acc);
        }
        __syncthreads();
    }
}

// ---------------------------------------------------------------------------
// reduce_stats: per-channel sum and sum-of-squares over n_rows rows.
// ---------------------------------------------------------------------------
template <int COUT>
__global__ __launch_bounds__(256) void reduce_stats(
    const float* __restrict__ out, float* __restrict__ stats, int n_rows)
{
    const int RPP = 256 / COUT;
    int c = threadIdx.x % COUT;
    float s = 0.f, ss = 0.f;
    int g = threadIdx.x / COUT;
    for (long long row = (long long)blockIdx.x * RPP + g; row < n_rows;
         row += (long long)gridDim.x * RPP) {
        float v = out[row * COUT + c];
        s += v;
        ss += v * v;
    }
    __shared__ float sh_s[256];
    __shared__ float sh_ss[256];
    sh_s[threadIdx.x] = s;
    sh_ss[threadIdx.x] = ss;
    __syncthreads();
    for (int off = 128; off >= COUT; off >>= 1) {
        if (threadIdx.x < off) {
            sh_s[threadIdx.x] += sh_s[threadIdx.x + off];
            sh_ss[threadIdx.x] += sh_ss[threadIdx.x + off];
        }
        __syncthreads();
    }
    if (threadIdx.x < COUT) {
        atomicAdd(&stats[c], sh_s[c]);
        atomicAdd(&stats[COUT + c], sh_ss[c]);
    }
}

// ---------------------------------------------------------------------------
// bn_skip: y = (v - mean) * rsqrt(var + eps) * gamma + beta + skip, in place.
// ---------------------------------------------------------------------------
template <int COUT>
__global__ __launch_bounds__(256) void bn_skip(
    float* __restrict__ out, const float* __restrict__ skip,
    const float* __restrict__ gamma, const float* __restrict__ beta,
    const float* __restrict__ stats, int n_rows)
{
    const int C4 = COUT / 4;
    long long idx = (long long)blockIdx.x * blockDim.x + threadIdx.x;
    long long total = (long long)n_rows * C4;
    if (idx >= total) return;
    int c4 = (int)(idx % C4);
    float4 v = ((const float4*)out)[idx];
    float4 sk = ((const float4*)skip)[idx];
    float inv_n = 1.f / (float)n_rows;
    float r[4] = {v.x, v.y, v.z, v.w};
    float skv[4] = {sk.x, sk.y, sk.z, sk.w};
#pragma unroll
    for (int j = 0; j < 4; ++j) {
        int c = c4 * 4 + j;
        float mean = stats[c] * inv_n;
        float var = stats[COUT + c] * inv_n - mean * mean;
        float scale = rsqrtf(var + EPS) * gamma[c];
        r[j] = (r[j] - mean) * scale + beta[c] + skv[j];
    }
    float4 res = {r[0], r[1], r[2], r[3]};
    ((float4*)out)[idx] = res;
}

extern "C" void kernel_launch(void* const* d_in, const int* in_sizes, int n_in,
                              void* d_out, int out_size, void* d_ws, size_t ws_size,
                              hipStream_t stream) {
    const float* x3    = (const float*)d_in[0];
    const float* skip3 = (const float*)d_in[1];
    const float* skip2 = (const float*)d_in[2];
    const float* skip1 = (const float*)d_in[3];
    const float* W3    = (const float*)d_in[4];
    const float* W2    = (const float*)d_in[5];
    const float* W1    = (const float*)d_in[6];
    const float* gamma3 = (const float*)d_in[7];
    const float* beta3  = (const float*)d_in[8];
    const float* gamma2 = (const float*)d_in[9];
    const float* beta2  = (const float*)d_in[10];
    const float* gamma1 = (const float*)d_in[11];
    const float* beta1  = (const float*)d_in[12];
    const int* in_idx3  = (const int*)d_in[13];
    const int* out_idx3 = (const int*)d_in[14];
    const int* in_idx2  = (const int*)d_in[15];
    const int* out_idx2 = (const int*)d_in[16];
    const int* in_idx1  = (const int*)d_in[17];
    const int* out_idx1 = (const int*)d_in[18];

    const int N3 = 40000, N2 = 160000, N1 = 640000, N0 = 2560000;
    const int K = 9;

    float* buf3  = (float*)d_ws;                    // N2 * 64
    float* buf2  = buf3 + (size_t)N2 * 64;          // N1 * 32
    float* stats = buf2 + (size_t)N1 * 32;          // 128 floats

    float* outp = (float*)d_out;                    // N0 * 32

    // ---------------- Level 3: x3[N3,128] -> buf3[N2,64] ----------------
    hipMemsetAsync(buf3, 0, (size_t)N2 * 64 * sizeof(float), stream);
    hipMemsetAsync(stats, 0, 128 * sizeof(float), stream);
    {
        const int RPB = 16;                 // 40000/16 = 2500 exact
        dim3 grid(N3 / RPB, K);
        scatter_gemm_l3_h2<RPB><<<grid, 256, 0, stream>>>(
            x3, W3, in_idx3, out_idx3, buf3, N3);
    }
    reduce_stats<64><<<1024, 256, 0, stream>>>(buf3, stats, N2);
    {
        long long tot = (long long)N2 * (64 / 4);
        bn_skip<64><<<(int)((tot + 255) / 256), 256, 0, stream>>>(
            buf3, skip3, gamma3, beta3, stats, N2);
    }

    // ---------------- Level 2: buf3[N2,64] -> buf2[N1,32] ----------------
    hipMemsetAsync(buf2, 0, (size_t)N1 * 32 * sizeof(float), stream);
    hipMemsetAsync(stats, 0, 128 * sizeof(float), stream);
    {
        const int RPB = 32;                 // 160000/32 = 5000 exact
        dim3 grid(N2 / RPB, K);
        scatter_gemm_h2<64, RPB><<<grid, 256, 0, stream>>>(
            buf3, W2, in_idx2, out_idx2, buf2, N2);
    }
    reduce_stats<32><<<2048, 256, 0, stream>>>(buf2, stats, N1);
    {
        long long tot = (long long)N1 * (32 / 4);
        bn_skip<32><<<(int)((tot + 255) / 256), 256, 0, stream>>>(
            buf2, skip2, gamma2, beta2, stats, N1);
    }

    // ---------------- Level 1: buf2[N1,32] -> d_out[N0,32] ----------------
    hipMemsetAsync(outp, 0, (size_t)N0 * 32 * sizeof(float), stream);
    hipMemsetAsync(stats, 0, 128 * sizeof(float), stream);
    {
        const int RPB = 64;
        dim3 grid((N1 + RPB - 1) / RPB, K);
        scatter_gemm_wreg<32, 32, RPB><<<grid, 256, 0, stream>>>(
            buf2, W1, in_idx1, out_idx1, outp, N1);
    }
    reduce_stats<32><<<4096, 256, 0, stream>>>(outp, stats, N0);
    {
        long long tot = (long long)N0 * (32 / 4);
        bn_skip<32><<<(int)((tot + 255) / 256), 256, 0, stream>>>(
            outp, skip1, gamma1, beta1, stats, N0);
    }
}